// Round 1
// baseline (8236.184 us; speedup 1.0000x reference)
//
#include <hip/hip_runtime.h>
#include <hip/hip_bf16.h>

#define T_STEPS 512
#define BATCH   64
#define IDIM    512
#define HDIM    1024
#define ODIM    512
#define NWG     128
#define TPB     256
#define JS      8            // hidden units per WG
#define GC      32           // gate cols per WG = 4*JS
#define KTOT    1536         // IDIM + HDIM

typedef __bf16 bf16_t;
typedef bf16_t bf16x8 __attribute__((ext_vector_type(8)));
typedef float  f32x4  __attribute__((ext_vector_type(4)));
typedef unsigned int u32;

__device__ __forceinline__ float sigmoidf_fast(float x) {
  return 1.0f / (1.0f + __expf(-x));
}
__device__ __forceinline__ float tanhf_fast(float x) {
  float ax = fabsf(x);
  float e  = __expf(-2.0f * ax);
  float t  = (1.0f - e) / (1.0f + e);
  return copysignf(t, x);
}

// ws layout: [0, 256KB): h double buffer (2 x 64 x 1024 bf16); then u32 counter.
#define HBUF_U32 (2 * BATCH * HDIM / 2)   // 65536 u32

__global__ void k_init(u32* ws_u32) {
  int i = blockIdx.x * blockDim.x + threadIdx.x;
  for (int idx = i; idx < HBUF_U32; idx += gridDim.x * blockDim.x) ws_u32[idx] = 0u;
  if (i == 0) ws_u32[HBUF_U32] = 0u;   // barrier counter
}

__global__ __launch_bounds__(TPB) void k_lstm(
    const float* __restrict__ X, const float* __restrict__ Wih,
    const float* __restrict__ Whh, const float* __restrict__ bih,
    const float* __restrict__ bhh, unsigned short* __restrict__ hbuf,
    u32* __restrict__ cnt) {
  __shared__ unsigned short Wl[GC * KTOT];   // 96KB swizzled bf16 weight slice
  __shared__ float gl[BATCH * GC];           // 8KB gate pre-activations

  const int wg   = blockIdx.x;
  const int tid  = threadIdx.x;
  const int lane = tid & 63;
  const int w    = tid >> 6;        // wave 0..3

  // ---- stage weight slice to LDS as bf16, XOR-swizzled ----
  // local row r in [0,32): gate = r>>3, jj = r&7 -> global gate row
  for (int idx = tid; idx < GC * KTOT; idx += TPB) {
    int r  = idx / KTOT;
    int k  = idx - r * KTOT;
    int gr = (r >> 3) * HDIM + wg * JS + (r & 7);
    float v = (k < IDIM) ? Wih[gr * IDIM + k] : Whh[gr * HDIM + (k - IDIM)];
    int byte = (r * KTOT + k) * 2;
    byte ^= ((r & 7) << 4);
    *(unsigned short*)((char*)Wl + byte) = __builtin_bit_cast(unsigned short, (bf16_t)v);
  }

  // ---- per-thread epilogue ownership: (b, jj0..jj0+1), c kept in registers ----
  const int eb  = tid >> 2;          // batch row 0..63
  const int ej0 = (tid & 3) * 2;     // jj in {0,2,4,6}
  float bias[4][2];
  #pragma unroll
  for (int g = 0; g < 4; ++g)
    #pragma unroll
    for (int q = 0; q < 2; ++q) {
      int gr = g * HDIM + wg * JS + ej0 + q;
      bias[g][q] = bih[gr] + bhh[gr];
    }
  float c0 = 0.f, c1 = 0.f;

  const int am = lane & 15;          // A-frag row within 16-tile
  const int kg = lane >> 4;          // k-group 0..3
  const int swz = (am & 7) << 4;     // row-swizzle for both n-tiles (16+am keeps am&7)

  __syncthreads();

  int cur = 0;
  for (int t = 0; t < T_STEPS; ++t) {
    f32x4 acc0 = {0.f, 0.f, 0.f, 0.f};
    f32x4 acc1 = {0.f, 0.f, 0.f, 0.f};
    const int b = 16 * w + am;
    const float* xrow = X + ((size_t)t * BATCH + b) * IDIM + kg * 8;
    const unsigned short* hrow = hbuf + (size_t)cur * BATCH * HDIM + b * HDIM + kg * 8;

    // X part: K = 0..511 (f32 -> bf16 on the fly)
    #pragma unroll 4
    for (int kc = 0; kc < 16; ++kc) {
      f32x4 u = *(const f32x4*)(xrow + kc * 32);
      f32x4 v = *(const f32x4*)(xrow + kc * 32 + 4);
      bf16x8 a;
      a[0] = (bf16_t)u[0]; a[1] = (bf16_t)u[1]; a[2] = (bf16_t)u[2]; a[3] = (bf16_t)u[3];
      a[4] = (bf16_t)v[0]; a[5] = (bf16_t)v[1]; a[6] = (bf16_t)v[2]; a[7] = (bf16_t)v[3];
      int kk  = kc * 32 + kg * 8;
      int by0 = (( am      * KTOT + kk) * 2) ^ swz;
      int by1 = (((16 + am) * KTOT + kk) * 2) ^ swz;
      bf16x8 b0 = *(const bf16x8*)((const char*)Wl + by0);
      bf16x8 b1 = *(const bf16x8*)((const char*)Wl + by1);
      acc0 = __builtin_amdgcn_mfma_f32_16x16x32_bf16(a, b0, acc0, 0, 0, 0);
      acc1 = __builtin_amdgcn_mfma_f32_16x16x32_bf16(a, b1, acc1, 0, 0, 0);
    }
    // h part: K = 512..1535 (bf16 direct)
    #pragma unroll 4
    for (int kc = 16; kc < 48; ++kc) {
      bf16x8 a = *(const bf16x8*)(hrow + (kc - 16) * 32);
      int kk  = kc * 32 + kg * 8;
      int by0 = (( am      * KTOT + kk) * 2) ^ swz;
      int by1 = (((16 + am) * KTOT + kk) * 2) ^ swz;
      bf16x8 b0 = *(const bf16x8*)((const char*)Wl + by0);
      bf16x8 b1 = *(const bf16x8*)((const char*)Wl + by1);
      acc0 = __builtin_amdgcn_mfma_f32_16x16x32_bf16(a, b0, acc0, 0, 0, 0);
      acc1 = __builtin_amdgcn_mfma_f32_16x16x32_bf16(a, b1, acc1, 0, 0, 0);
    }

    // scatter accumulators: D row = kg*4+i, col = am
    {
      int row = kg * 4;
      int mb  = 16 * w;
      #pragma unroll
      for (int i2 = 0; i2 < 4; ++i2) {
        gl[(mb + row + i2) * GC + am]      = acc0[i2];
        gl[(mb + row + i2) * GC + 16 + am] = acc1[i2];
      }
    }
    __syncthreads();

    // epilogue: gates -> c,h ; write h slice (bf16) to next buffer
    {
      const float* gb = gl + eb * GC;
      float pi0 = gb[ 0 + ej0]     + bias[0][0];
      float pi1 = gb[ 0 + ej0 + 1] + bias[0][1];
      float pf0 = gb[ 8 + ej0]     + bias[1][0];
      float pf1 = gb[ 8 + ej0 + 1] + bias[1][1];
      float pg0 = gb[16 + ej0]     + bias[2][0];
      float pg1 = gb[16 + ej0 + 1] + bias[2][1];
      float po0 = gb[24 + ej0]     + bias[3][0];
      float po1 = gb[24 + ej0 + 1] + bias[3][1];
      c0 = sigmoidf_fast(pf0) * c0 + sigmoidf_fast(pi0) * tanhf_fast(pg0);
      c1 = sigmoidf_fast(pf1) * c1 + sigmoidf_fast(pi1) * tanhf_fast(pg1);
      float h0 = sigmoidf_fast(po0) * tanhf_fast(c0);
      float h1 = sigmoidf_fast(po1) * tanhf_fast(c1);
      u32 pack = (u32)__builtin_bit_cast(unsigned short, (bf16_t)h0)
               | ((u32)__builtin_bit_cast(unsigned short, (bf16_t)h1) << 16);
      unsigned short* hn = hbuf + (size_t)(cur ^ 1) * BATCH * HDIM;
      *(u32*)(hn + eb * HDIM + wg * JS + ej0) = pack;
    }

    // grid barrier: release(wb L2) -> arrive -> poll -> acquire(inv L2)
    __syncthreads();   // drains each wave's vmcnt: h stores are in L2
    if (tid == 0) {
      __threadfence();                    // writeback dirty L2 lines to LLC
      atomicAdd(cnt, 1u);
      u32 target = (u32)(t + 1) * (u32)NWG;
      while (__hip_atomic_load(cnt, __ATOMIC_RELAXED, __HIP_MEMORY_SCOPE_AGENT) < target) {
        __builtin_amdgcn_s_sleep(1);
      }
      __builtin_amdgcn_fence(__ATOMIC_ACQUIRE, "agent");  // invalidate stale L1/L2
    }
    __syncthreads();
    cur ^= 1;
  }
}

__global__ __launch_bounds__(TPB) void k_out(
    const unsigned short* __restrict__ hfin, const float* __restrict__ Who,
    const float* __restrict__ bho, float* __restrict__ out) {
  int gid = blockIdx.x * TPB + threadIdx.x;  // 0..32767
  int b   = gid & 63;
  int oc  = gid >> 6;
  const unsigned short* hrow = hfin + b * HDIM;
  const float* wrow = Who + oc * HDIM;
  float s = bho[oc];
  for (int k = 0; k < HDIM; k += 8) {
    bf16x8 hv = *(const bf16x8*)(hrow + k);
    f32x4 w0 = *(const f32x4*)(wrow + k);
    f32x4 w1 = *(const f32x4*)(wrow + k + 4);
    s += (float)hv[0] * w0[0] + (float)hv[1] * w0[1] + (float)hv[2] * w0[2] + (float)hv[3] * w0[3]
       + (float)hv[4] * w1[0] + (float)hv[5] * w1[1] + (float)hv[6] * w1[2] + (float)hv[7] * w1[3];
  }
  out[b * ODIM + oc] = s;
}

extern "C" void kernel_launch(void* const* d_in, const int* in_sizes, int n_in,
                              void* d_out, int out_size, void* d_ws, size_t ws_size,
                              hipStream_t stream) {
  const float* X   = (const float*)d_in[0];
  const float* Wih = (const float*)d_in[1];
  const float* Whh = (const float*)d_in[2];
  const float* bih = (const float*)d_in[3];
  const float* bhh = (const float*)d_in[4];
  const float* Who = (const float*)d_in[5];
  const float* bho = (const float*)d_in[6];

  u32* ws32 = (u32*)d_ws;
  unsigned short* hbuf = (unsigned short*)d_ws;
  u32* cnt = ws32 + HBUF_U32;

  k_init<<<64, TPB, 0, stream>>>(ws32);
  k_lstm<<<NWG, TPB, 0, stream>>>(X, Wih, Whh, bih, bhh, hbuf, cnt);
  k_out<<<(BATCH * ODIM) / TPB, TPB, 0, stream>>>(hbuf, Who, bho, (float*)d_out);
}

// Round 2
// 6335.338 us; speedup vs baseline: 1.3000x; 1.3000x over previous
//
#include <hip/hip_runtime.h>
#include <hip/hip_bf16.h>

#define T_STEPS 512
#define BATCH   64
#define IDIM    512
#define HDIM    1024
#define ODIM    512
#define NWG     128
#define TPB     256
#define JS      8            // hidden units per WG
#define GC      32           // gate cols per WG = 4*JS
#define KTOT    1536         // IDIM + HDIM

typedef __bf16 bf16_t;
typedef bf16_t bf16x8 __attribute__((ext_vector_type(8)));
typedef float  f32x4  __attribute__((ext_vector_type(4)));
typedef unsigned short u16;
typedef unsigned int   u32;
typedef u16 u16x8 __attribute__((ext_vector_type(8)));

// ws layout (u32 units): [0,65536) h double buffer (2x64x1024 bf16);
// [65536, 65792) 8 barrier counters spaced 128B; then X_bf16 (16.7M u16).
#define HBUF_U32 65536
#define CNT_U32  256
#define XB_U16_OFF (2 * (HBUF_U32 + CNT_U32))

// gl swizzle: bank = (col + 2*row) & 31 -> epilogue reads 2-way, scatter ~2-way
#define GL(row, col) ((row) * GC + (((col) + 2 * (row)) & 31))

__device__ __forceinline__ float sigmoidf_fast(float x) {
  return 1.0f / (1.0f + __expf(-x));
}
__device__ __forceinline__ float tanhf_fast(float x) {
  float ax = fabsf(x);
  float e  = __expf(-2.0f * ax);
  return copysignf((1.0f - e) / (1.0f + e), x);
}

__global__ void k_init(u32* w) {
  int i = blockIdx.x * blockDim.x + threadIdx.x;
  for (int idx = i; idx < HBUF_U32 + CNT_U32; idx += gridDim.x * blockDim.x) w[idx] = 0u;
}

__global__ __launch_bounds__(TPB) void k_xcvt(const float* __restrict__ X,
                                              u16* __restrict__ Xb) {
  size_t i = ((size_t)blockIdx.x * TPB + threadIdx.x) * 8;
  f32x4 a = *(const f32x4*)(X + i);
  f32x4 b = *(const f32x4*)(X + i + 4);
  u16x8 o;
  o[0] = __builtin_bit_cast(u16, (bf16_t)a[0]);
  o[1] = __builtin_bit_cast(u16, (bf16_t)a[1]);
  o[2] = __builtin_bit_cast(u16, (bf16_t)a[2]);
  o[3] = __builtin_bit_cast(u16, (bf16_t)a[3]);
  o[4] = __builtin_bit_cast(u16, (bf16_t)b[0]);
  o[5] = __builtin_bit_cast(u16, (bf16_t)b[1]);
  o[6] = __builtin_bit_cast(u16, (bf16_t)b[2]);
  o[7] = __builtin_bit_cast(u16, (bf16_t)b[3]);
  *(u16x8*)(Xb + i) = o;
}

__global__ __launch_bounds__(TPB, 1) void k_lstm(
    const u16* __restrict__ Xb, const float* __restrict__ Wih,
    const float* __restrict__ Whh, const float* __restrict__ bih,
    const float* __restrict__ bhh, u16* __restrict__ hbuf,
    u32* __restrict__ cnt) {
  __shared__ u16 Wl[GC * KTOT];    // 96KB swizzled bf16 weight slice
  __shared__ float gl[BATCH * GC]; // 8KB gate pre-activations (bias included)

  const int wg   = blockIdx.x;
  const int tid  = threadIdx.x;
  const int lane = tid & 63;
  const int w    = tid >> 6;

  // ---- stage weight slice to LDS as bf16, XOR-swizzled ----
  for (int idx = tid; idx < GC * KTOT; idx += TPB) {
    int r  = idx / KTOT;
    int k  = idx - r * KTOT;
    int gr = (r >> 3) * HDIM + wg * JS + (r & 7);
    float v = (k < IDIM) ? Wih[gr * IDIM + k] : Whh[gr * HDIM + (k - IDIM)];
    int byte = (r * KTOT + k) * 2;
    byte ^= ((r & 7) << 4);
    *(u16*)((char*)Wl + byte) = __builtin_bit_cast(u16, (bf16_t)v);
  }

  const int am  = lane & 15;
  const int kg  = lane >> 4;
  const int swz = (am & 7) << 4;
  const int b   = 16 * w + am;

  // bias folded into accumulator init: col am -> gate am>>3, col 16+am -> gate 2+(am>>3)
  const int jA  = am & 7;
  const int grA = (am >> 3) * HDIM + wg * JS + jA;
  const int grB = (2 + (am >> 3)) * HDIM + wg * JS + jA;
  const float biasA = bih[grA] + bhh[grA];
  const float biasB = bih[grB] + bhh[grB];

  const int eb  = tid >> 2;
  const int ej0 = (tid & 3) * 2;
  float c0 = 0.f, c1 = 0.f;

  __syncthreads();

  // prefetch X(0) into registers (bf16, pre-converted)
  bf16x8 xr[16];
  {
    const u16* xrow = Xb + (size_t)b * IDIM + kg * 8;
    #pragma unroll
    for (int kc = 0; kc < 16; ++kc) xr[kc] = *(const bf16x8*)(xrow + kc * 32);
  }

  int cur = 0;
  for (int t = 0; t < T_STEPS; ++t) {
    // issue ALL h loads first (LLC latency paid once, hidden under X MFMAs)
    bf16x8 hr[32];
    const u16* hrow = hbuf + (size_t)cur * BATCH * HDIM + b * HDIM + kg * 8;
    #pragma unroll
    for (int kc = 0; kc < 32; ++kc) hr[kc] = *(const bf16x8*)(hrow + kc * 32);

    f32x4 acc0 = {biasA, biasA, biasA, biasA};
    f32x4 acc1 = {biasB, biasB, biasB, biasB};

    // X part from prefetched registers
    #pragma unroll
    for (int kc = 0; kc < 16; ++kc) {
      int kk = kc * 32 + kg * 8;
      bf16x8 b0 = *(const bf16x8*)((const char*)Wl + ((( am      * KTOT + kk) * 2) ^ swz));
      bf16x8 b1 = *(const bf16x8*)((const char*)Wl + ((((16 + am) * KTOT + kk) * 2) ^ swz));
      acc0 = __builtin_amdgcn_mfma_f32_16x16x32_bf16(xr[kc], b0, acc0, 0, 0, 0);
      acc1 = __builtin_amdgcn_mfma_f32_16x16x32_bf16(xr[kc], b1, acc1, 0, 0, 0);
    }

    // prefetch X(t+1): immutable data, safe across the barrier; overlaps h MFMAs + barrier
    if (t != T_STEPS - 1) {
      const u16* xn = Xb + ((size_t)(t + 1) * BATCH + b) * IDIM + kg * 8;
      #pragma unroll
      for (int kc = 0; kc < 16; ++kc) xr[kc] = *(const bf16x8*)(xn + kc * 32);
    }

    // h part
    #pragma unroll
    for (int kc = 0; kc < 32; ++kc) {
      int kk = IDIM + kc * 32 + kg * 8;
      bf16x8 b0 = *(const bf16x8*)((const char*)Wl + ((( am      * KTOT + kk) * 2) ^ swz));
      bf16x8 b1 = *(const bf16x8*)((const char*)Wl + ((((16 + am) * KTOT + kk) * 2) ^ swz));
      acc0 = __builtin_amdgcn_mfma_f32_16x16x32_bf16(hr[kc], b0, acc0, 0, 0, 0);
      acc1 = __builtin_amdgcn_mfma_f32_16x16x32_bf16(hr[kc], b1, acc1, 0, 0, 0);
    }

    // scatter accumulators (swizzled): D row = kg*4+i, col = am / 16+am
    {
      int row0 = 16 * w + kg * 4;
      #pragma unroll
      for (int i2 = 0; i2 < 4; ++i2) {
        gl[GL(row0 + i2, am)]      = acc0[i2];
        gl[GL(row0 + i2, 16 + am)] = acc1[i2];
      }
    }
    __syncthreads();

    // epilogue: activations (bias already in), c in regs, write h slice bf16
    {
      float pi0 = gl[GL(eb,  0 + ej0)], pi1 = gl[GL(eb,  1 + ej0)];
      float pf0 = gl[GL(eb,  8 + ej0)], pf1 = gl[GL(eb,  9 + ej0)];
      float pg0 = gl[GL(eb, 16 + ej0)], pg1 = gl[GL(eb, 17 + ej0)];
      float po0 = gl[GL(eb, 24 + ej0)], po1 = gl[GL(eb, 25 + ej0)];
      c0 = sigmoidf_fast(pf0) * c0 + sigmoidf_fast(pi0) * tanhf_fast(pg0);
      c1 = sigmoidf_fast(pf1) * c1 + sigmoidf_fast(pi1) * tanhf_fast(pg1);
      float h0 = sigmoidf_fast(po0) * tanhf_fast(c0);
      float h1 = sigmoidf_fast(po1) * tanhf_fast(c1);
      u32 pack = (u32)__builtin_bit_cast(u16, (bf16_t)h0)
               | ((u32)__builtin_bit_cast(u16, (bf16_t)h1) << 16);
      *(u32*)(hbuf + (size_t)(cur ^ 1) * BATCH * HDIM + eb * HDIM + wg * JS + ej0) = pack;
    }

    // grid barrier: release(wb L2) -> arrive(8-way split counters) -> poll -> acquire(inv L2)
    __syncthreads();   // s_barrier semantics drain each wave's outstanding stores
    if (tid < 64) {
      __builtin_amdgcn_fence(__ATOMIC_RELEASE, "agent");
      if (lane == 0) atomicAdd(&cnt[(wg & 7) * 32], 1u);
      u32 target = (u32)(t + 1) * (u32)NWG;
      while (true) {
        u32 v = (lane < 8)
          ? __hip_atomic_load(&cnt[lane * 32], __ATOMIC_RELAXED, __HIP_MEMORY_SCOPE_AGENT)
          : 0u;
        v += __shfl_xor(v, 1);
        v += __shfl_xor(v, 2);
        v += __shfl_xor(v, 4);
        if (__shfl(v, 0) >= target) break;
        __builtin_amdgcn_s_sleep(2);
      }
      __builtin_amdgcn_fence(__ATOMIC_ACQUIRE, "agent");
    }
    __syncthreads();
    cur ^= 1;
  }
}

__global__ __launch_bounds__(TPB) void k_out(
    const u16* __restrict__ hfin, const float* __restrict__ Who,
    const float* __restrict__ bho, float* __restrict__ out) {
  int gid = blockIdx.x * TPB + threadIdx.x;  // 0..32767
  int b   = gid & 63;
  int oc  = gid >> 6;
  const u16* hrow = hfin + b * HDIM;
  const float* wrow = Who + oc * HDIM;
  float s = bho[oc];
  for (int k = 0; k < HDIM; k += 8) {
    bf16x8 hv = *(const bf16x8*)(hrow + k);
    f32x4 w0 = *(const f32x4*)(wrow + k);
    f32x4 w1 = *(const f32x4*)(wrow + k + 4);
    s += (float)hv[0] * w0[0] + (float)hv[1] * w0[1] + (float)hv[2] * w0[2] + (float)hv[3] * w0[3]
       + (float)hv[4] * w1[0] + (float)hv[5] * w1[1] + (float)hv[6] * w1[2] + (float)hv[7] * w1[3];
  }
  out[b * ODIM + oc] = s;
}

extern "C" void kernel_launch(void* const* d_in, const int* in_sizes, int n_in,
                              void* d_out, int out_size, void* d_ws, size_t ws_size,
                              hipStream_t stream) {
  const float* X   = (const float*)d_in[0];
  const float* Wih = (const float*)d_in[1];
  const float* Whh = (const float*)d_in[2];
  const float* bih = (const float*)d_in[3];
  const float* bhh = (const float*)d_in[4];
  const float* Who = (const float*)d_in[5];
  const float* bho = (const float*)d_in[6];

  u32* ws32 = (u32*)d_ws;
  u16* hbuf = (u16*)d_ws;
  u32* cnt  = ws32 + HBUF_U32;
  u16* Xb   = (u16*)d_ws + XB_U16_OFF;

  k_init<<<64, TPB, 0, stream>>>(ws32);
  // X: 512*64*512 = 16,777,216 f32 -> bf16 ; 8 elems/thread
  k_xcvt<<<(T_STEPS * BATCH * IDIM) / (TPB * 8), TPB, 0, stream>>>(X, Xb);
  k_lstm<<<NWG, TPB, 0, stream>>>(Xb, Wih, Whh, bih, bhh, hbuf, cnt);
  k_out<<<(BATCH * ODIM) / TPB, TPB, 0, stream>>>(hbuf, Who, bho, (float*)d_out);
}